// Round 4
// baseline (700.026 us; speedup 1.0000x reference)
//
#include <hip/hip_runtime.h>
#include <hip/hip_bf16.h>
#include <stdint.h>

// Problem constants
#define B_N 1024
#define S_N 65536
#define D_N 512
#define NS 32                 // s-chunks; grid = 8 batch-blocks x NS = 256 = 1 block/CU
#define SC (S_N / NS)         // 2048 s per block
#define SB 128                // s subtile (P tile = 128 b x 128 s in LDS)
#define NSUB (SC / SB)        // 16

typedef __attribute__((ext_vector_type(8))) short bf16x8;   // 8 bf16 in 4 VGPRs
typedef __attribute__((ext_vector_type(4))) float f32x4;

// ---- workspace layout (bytes) ----
#define OFF_MBF   ((size_t)0)                                  // M bf16 (s,d)   64 MiB
#define OFF_MT    (OFF_MBF + (size_t)S_N * D_N * 2)            // M^T bf16 (d,s) 64 MiB
#define OFF_XBF   (OFF_MT  + (size_t)D_N * S_N * 2)            // X bf16         1 MiB
#define OFF_RX    (OFF_XBF + (size_t)B_N * D_N * 2)            // 8*log2e*rsqrt(|x|^2)  4 KiB
#define OFF_RM    (OFF_RX  + (size_t)B_N * 4)                  // rsqrt(|m|^2)   256 KiB
#define OFF_LSUM  (OFF_RM  + (size_t)S_N * 4)                  // softmax denom  4 KiB
#define OFF_OPART (OFF_LSUM + (size_t)B_N * 4)                 // PV partials    64 MiB

__device__ __forceinline__ unsigned short f2bf(float f) {
  unsigned u = __builtin_bit_cast(unsigned, f);
  u += 0x7fffu + ((u >> 16) & 1u);          // RNE
  return (unsigned short)(u >> 16);
}

__device__ __forceinline__ void stage16(const unsigned short* g, unsigned short* l) {
  // async global->LDS, 16B/lane; LDS dest is wave-uniform base + lane*16
  __builtin_amdgcn_global_load_lds(
      (const __attribute__((address_space(1))) void*)g,
      (__attribute__((address_space(3))) void*)l, 16, 0, 0);
}

// ---------------- prep X: bf16 convert + rx = 8*log2e*rsqrt(||x||^2) ----------------
__global__ void k_prep_x(const float* __restrict__ X, unsigned short* __restrict__ Xbf,
                         float* __restrict__ rx) {
  const int row = blockIdx.x;
  const int t = threadIdx.x;  // 0..127
  float4 v = ((const float4*)(X + (size_t)row * D_N))[t];
  float ss = v.x*v.x + v.y*v.y + v.z*v.z + v.w*v.w;
  ushort4 o; o.x = f2bf(v.x); o.y = f2bf(v.y); o.z = f2bf(v.z); o.w = f2bf(v.w);
  ((ushort4*)(Xbf + (size_t)row * D_N))[t] = o;
  #pragma unroll
  for (int m = 1; m < 64; m <<= 1) ss += __shfl_xor(ss, m);
  __shared__ float partial[2];
  if ((t & 63) == 0) partial[t >> 6] = ss;
  __syncthreads();
  if (t == 0) rx[row] = 11.541560327111707f * rsqrtf(fmaxf(partial[0] + partial[1], 1e-24f));
}

// ------- prep M: bf16 convert, LDS-transpose to Mt, rm = rsqrt(||m||^2) -------
__global__ void k_prep_m(const float* __restrict__ M, unsigned short* __restrict__ Mbf,
                         unsigned short* __restrict__ Mt, float* __restrict__ rm) {
  __shared__ float ts[64 * 65];             // 64x64 tile, +1 pad -> conflict-free transpose
  const int t = threadIdx.x;                // 256
  const int s0 = blockIdx.x * 64;
  const int r = t >> 2, cq = t & 3;
  const int c = t >> 2, sq = t & 3;
  float ss = 0.f;
  for (int ct = 0; ct < 8; ++ct) {
    float f[16];
    const float4* src = (const float4*)(M + (size_t)(s0 + r) * D_N + ct * 64 + cq * 16);
    #pragma unroll
    for (int k = 0; k < 4; ++k) {
      float4 v = src[k];
      f[4*k+0] = v.x; f[4*k+1] = v.y; f[4*k+2] = v.z; f[4*k+3] = v.w;
    }
    union { unsigned short u[16]; uint4 v4[2]; } pk;
    #pragma unroll
    for (int j = 0; j < 16; ++j) {
      ss += f[j] * f[j];
      pk.u[j] = f2bf(f[j]);
      ts[r * 65 + cq * 16 + j] = f[j];
    }
    uint4* dst = (uint4*)(Mbf + (size_t)(s0 + r) * D_N + ct * 64 + cq * 16);
    dst[0] = pk.v4[0]; dst[1] = pk.v4[1];
    __syncthreads();
    union { unsigned short u[16]; uint4 v4[2]; } pt;
    #pragma unroll
    for (int j = 0; j < 16; ++j) pt.u[j] = f2bf(ts[(sq * 16 + j) * 65 + c]);
    uint4* dt = (uint4*)(Mt + (size_t)(ct * 64 + c) * S_N + s0 + sq * 16);
    dt[0] = pt.v4[0]; dt[1] = pt.v4[1];
    __syncthreads();
  }
  ss += __shfl_xor(ss, 1);
  ss += __shfl_xor(ss, 2);
  if (cq == 0) rm[s0 + r] = rsqrtf(fmaxf(ss, 1e-24f));
}

// ================= fused QK -> exp -> PV, 4 waves, X-resident, operands-from-global =================
// 256 threads = 4 waves = 1 wave/SIMD -> 512-reg budget (no spills).
// X (128b x 512k bf16, 128 KiB) DMA'd into LDS ONCE, XOR-swizzled, resident for
// the whole kernel. M (QK A-operand) and Mt (PV B-operand) are read directly
// global->registers as 16B-contiguous MFMA fragments (L2-resident via XCD
// swizzle) -- they never touch LDS. P (128x128 bf16, 32 KiB) is the only other
// LDS tile. Only 2 barriers per subtile (P producer/consumer). K-loops use
// depth-2 register double-buffering of fragments (all indices compile-time).
// QK: wave grid 2s x 2b, tile 64x64 (accP = 64 VGPR).
// PV: wave grid 1b x 4d, tile 128b x 128d (accO = 256 VGPR).
__global__ __launch_bounds__(256, 1) void k_fused(
    const unsigned short* __restrict__ Xbf, const unsigned short* __restrict__ Mbf,
    const unsigned short* __restrict__ Mt, const float* __restrict__ rx,
    const float* __restrict__ rminv, float* __restrict__ lsum,
    float* __restrict__ Opart) {
  __shared__ unsigned short Xs[128 * 512];  // 128 KiB, resident, swizzled
  __shared__ unsigned short Ps[128 * 128];  // 32 KiB P tile, swizzled

  const int t = threadIdx.x;               // 0..255
  const int w = t >> 6, lane = t & 63, quad = lane >> 4, l15 = lane & 15;
  const int qs2 = w >> 1, qb2 = w & 1;     // QK wave grid: 2 s-halves x 2 b-halves
  const int x7 = l15 & 7;                  // row&7 for all swizzled accesses (rows are ..+l15)

  // XCD swizzle: 8 batch-blocks sharing an s-chunk land on one XCD (M+Mt chunk = 4 MiB L2)
  const int bid = blockIdx.x;
  const int xcd = bid & 7, slot = bid >> 3;
  const int bblk = slot & 7;
  const int chunk = xcd * 4 + (slot >> 3);
  const int b0 = bblk * 128;
  const int s0 = chunk * SC;

  // ---------------- stage X once (DMA, source-side inverse swizzle) ----------------
  #pragma unroll
  for (int i = 0; i < 32; ++i) {
    const int row = i * 4 + w;
    stage16(Xbf + (size_t)(b0 + row) * D_N + ((lane ^ (row & 7)) << 3),
            Xs + i * 2048 + w * 512);
  }
  asm volatile("s_waitcnt vmcnt(0)" ::: "memory");
  __builtin_amdgcn_s_barrier();

  f32x4 accO[8][8];                        // 256 VGPR: b-frag i (x16), d-frag j (x16)
  #pragma unroll
  for (int i = 0; i < 8; ++i)
    #pragma unroll
    for (int j = 0; j < 8; ++j) accO[i][j] = (f32x4){0.f, 0.f, 0.f, 0.f};

  float ls[4] = {0.f, 0.f, 0.f, 0.f};
  float rxj[4];
  #pragma unroll
  for (int j = 0; j < 4; ++j) rxj[j] = rx[b0 + qb2 * 64 + j * 16 + l15];

  // global fragment base pointers (per-lane)
  const unsigned short* gT0 = Mt + (size_t)(w * 128 + l15) * S_N + (size_t)s0 + quad * 8;

  for (int sub = 0; sub < NSUB; ++sub) {
    const int sS = s0 + sub * SB;

    // ---------------- QK: accP[64s x 64b per wave], K=512, depth-2 dbuf ----------------
    f32x4 accP[4][4];
    #pragma unroll
    for (int i = 0; i < 4; ++i)
      #pragma unroll
      for (int j = 0; j < 4; ++j) accP[i][j] = (f32x4){0.f, 0.f, 0.f, 0.f};

    const unsigned short* gM = Mbf + (size_t)(sS + qs2 * 64 + l15) * D_N + quad * 8;
    const int xrow = qb2 * 64 + l15;       // +j*16

    bf16x8 aB[2][4], xB[2][4];
    #pragma unroll
    for (int i = 0; i < 4; ++i)
      aB[0][i] = *(const bf16x8*)(gM + (size_t)(i * 16) * D_N);
    #pragma unroll
    for (int j = 0; j < 4; ++j)
      xB[0][j] = *(const bf16x8*)&Xs[(xrow + j * 16) * 512 + ((quad ^ x7) << 3)];

    #pragma unroll
    for (int ks = 0; ks < 16; ++ks) {
      const int cur = ks & 1, nxt = cur ^ 1;
      if (ks < 15) {
        #pragma unroll
        for (int i = 0; i < 4; ++i)
          aB[nxt][i] = *(const bf16x8*)(gM + (size_t)(i * 16) * D_N + (ks + 1) * 32);
        const int c = (ks + 1) * 4 + quad;
        #pragma unroll
        for (int j = 0; j < 4; ++j)
          xB[nxt][j] = *(const bf16x8*)&Xs[(xrow + j * 16) * 512 + ((c ^ x7) << 3)];
      }
      #pragma unroll
      for (int i = 0; i < 4; ++i)
        #pragma unroll
        for (int j = 0; j < 4; ++j)
          accP[i][j] = __builtin_amdgcn_mfma_f32_16x16x32_bf16(aB[cur][i], xB[cur][j], accP[i][j], 0, 0, 0);
    }

    // ------------- epilogue: p = exp2(dot*rx_b*rm_s), rowsum, P -> LDS -------------
    // C layout: s = qs2*64 + i*16 + quad*4 + r (4 consecutive), b = qb2*64 + j*16 + l15
    #pragma unroll
    for (int i = 0; i < 4; ++i) {
      const float4 rm = *(const float4*)&rminv[sS + qs2 * 64 + i * 16 + quad * 4];
      const int c16 = qs2 * 8 + i * 2 + (quad >> 1);
      #pragma unroll
      for (int j = 0; j < 4; ++j) {
        const float p0 = exp2f(accP[i][j][0] * rxj[j] * rm.x);
        const float p1 = exp2f(accP[i][j][1] * rxj[j] * rm.y);
        const float p2 = exp2f(accP[i][j][2] * rxj[j] * rm.z);
        const float p3 = exp2f(accP[i][j][3] * rxj[j] * rm.w);
        ls[j] += (p0 + p1) + (p2 + p3);
        const int brow = qb2 * 64 + j * 16 + l15;
        uint2 pk;
        pk.x = (unsigned)f2bf(p0) | ((unsigned)f2bf(p1) << 16);
        pk.y = (unsigned)f2bf(p2) | ((unsigned)f2bf(p3) << 16);
        *(uint2*)&Ps[brow * 128 + (((c16 ^ x7) << 3) | ((quad & 1) << 2))] = pk;
      }
    }
    asm volatile("s_waitcnt lgkmcnt(0)" ::: "memory");
    __builtin_amdgcn_s_barrier();          // P visible to all waves

    // ---------------- PV: accO[128b x 128d per wave], K=128, depth-2 dbuf ----------------
    const unsigned short* gT = gT0 + sub * SB;
    bf16x8 mB[2][8], pB[2][8];
    #pragma unroll
    for (int j = 0; j < 8; ++j)
      mB[0][j] = *(const bf16x8*)(gT + (size_t)(j * 16) * S_N);
    #pragma unroll
    for (int i = 0; i < 8; ++i)
      pB[0][i] = *(const bf16x8*)&Ps[(i * 16 + l15) * 128 + ((quad ^ x7) << 3)];

    #pragma unroll
    for (int kk = 0; kk < 4; ++kk) {
      const int cur = kk & 1, nxt = cur ^ 1;
      if (kk < 3) {
        #pragma unroll
        for (int j = 0; j < 8; ++j)
          mB[nxt][j] = *(const bf16x8*)(gT + (size_t)(j * 16) * S_N + (kk + 1) * 32);
        const int c = (kk + 1) * 4 + quad;
        #pragma unroll
        for (int i = 0; i < 8; ++i)
          pB[nxt][i] = *(const bf16x8*)&Ps[(i * 16 + l15) * 128 + ((c ^ x7) << 3)];
      }
      #pragma unroll
      for (int i = 0; i < 8; ++i)
        #pragma unroll
        for (int j = 0; j < 8; ++j)
          accO[i][j] = __builtin_amdgcn_mfma_f32_16x16x32_bf16(pB[cur][i], mB[cur][j], accO[i][j], 0, 0, 0);
    }
    asm volatile("s_waitcnt lgkmcnt(0)" ::: "memory");
    __builtin_amdgcn_s_barrier();          // P reads done before next epilogue writes
  }

  // ---------------- write O partials ----------------
  // accO C layout: b = i*16 + quad*4 + r, d = w*128 + j*16 + l15
  float* Od = Opart + (size_t)chunk * ((size_t)B_N * D_N);
  #pragma unroll
  for (int i = 0; i < 8; ++i)
    #pragma unroll
    for (int r = 0; r < 4; ++r) {
      const int bb = b0 + i * 16 + quad * 4 + r;
      #pragma unroll
      for (int j = 0; j < 8; ++j) {
        const int d = w * 128 + j * 16 + l15;
        Od[(size_t)bb * D_N + d] = accO[i][j][r];
      }
    }

  // ---------------- lsum: quad-reduce, cross-wave via LDS, one atomic per b ----------------
  __syncthreads();
  float* red = (float*)Ps;                   // 4 waves x 64 b-slots
  #pragma unroll
  for (int j = 0; j < 4; ++j) {
    float v = ls[j];
    v += __shfl_xor(v, 16);
    v += __shfl_xor(v, 32);
    if (lane < 16) red[w * 64 + j * 16 + lane] = v;
  }
  __syncthreads();
  if (t < 128) {
    // waves (qs2=0,qs2=1) sharing b-range: slots t and t+128
    float s = red[t] + red[t + 128];
    unsafeAtomicAdd(&lsum[b0 + t], s);
  }
}

// ---------------- combine: out = (sum_ks Opart) / lsum ----------------
__global__ void k_combine(const float* __restrict__ Opart, const float* __restrict__ lsum,
                          float* __restrict__ out) {
  const int idx = blockIdx.x * 256 + threadIdx.x;  // float4 index, 131072 total
  const int b = idx >> 7;
  float4 s = {0.f, 0.f, 0.f, 0.f};
  #pragma unroll
  for (int ks = 0; ks < NS; ++ks) {
    float4 v = ((const float4*)Opart)[(size_t)ks * (B_N * D_N / 4) + idx];
    s.x += v.x; s.y += v.y; s.z += v.z; s.w += v.w;
  }
  const float inv = 1.0f / lsum[b];
  s.x *= inv; s.y *= inv; s.z *= inv; s.w *= inv;
  ((float4*)out)[idx] = s;
}

extern "C" void kernel_launch(void* const* d_in, const int* in_sizes, int n_in,
                              void* d_out, int out_size, void* d_ws, size_t ws_size,
                              hipStream_t stream) {
  const float* X = (const float*)d_in[0];
  const float* M = (const float*)d_in[1];
  char* ws = (char*)d_ws;
  unsigned short* Mbf = (unsigned short*)(ws + OFF_MBF);
  unsigned short* Mt  = (unsigned short*)(ws + OFF_MT);
  unsigned short* Xbf = (unsigned short*)(ws + OFF_XBF);
  float* rxv  = (float*)(ws + OFF_RX);
  float* rmv  = (float*)(ws + OFF_RM);
  float* lsum = (float*)(ws + OFF_LSUM);
  float* Opart = (float*)(ws + OFF_OPART);

  hipMemsetAsync(lsum, 0, B_N * sizeof(float), stream);
  k_prep_x<<<dim3(B_N), 128, 0, stream>>>(X, Xbf, rxv);
  k_prep_m<<<dim3(S_N / 64), 256, 0, stream>>>(M, Mbf, Mt, rmv);
  k_fused<<<dim3(8 * NS), 256, 0, stream>>>(Xbf, Mbf, Mt, rxv, rmv, lsum, Opart);
  k_combine<<<dim3(B_N * D_N / 4 / 256), 256, 0, stream>>>(Opart, lsum, (float*)d_out);
}

// Round 6
// 489.316 us; speedup vs baseline: 1.4306x; 1.4306x over previous
//
#include <hip/hip_runtime.h>
#include <hip/hip_bf16.h>
#include <stdint.h>

// Problem constants
#define B_N 1024
#define S_N 65536
#define D_N 512
#define NS 32                 // s-chunks; grid = 8 batch-blocks x NS = 256 = 1 block/CU
#define SC (S_N / NS)         // 2048 s per block
#define SB 256                // s subtile (P tile = 128 b x 256 s in LDS)
#define NSUB (SC / SB)        // 8

typedef __attribute__((ext_vector_type(8))) short bf16x8;   // 8 bf16 in 4 VGPRs
typedef __attribute__((ext_vector_type(4))) float f32x4;
typedef __attribute__((ext_vector_type(16))) float f32x16;  // 32x32 MFMA accumulator

// ---- workspace layout (bytes) ----
#define OFF_MBF   ((size_t)0)                                  // M bf16 (s,d)   64 MiB
#define OFF_MT    (OFF_MBF + (size_t)S_N * D_N * 2)            // M^T bf16 (d,s) 64 MiB
#define OFF_XBF   (OFF_MT  + (size_t)D_N * S_N * 2)            // X bf16         1 MiB
#define OFF_RX    (OFF_XBF + (size_t)B_N * D_N * 2)            // 8*log2e*rsqrt(|x|^2)  4 KiB
#define OFF_RM    (OFF_RX  + (size_t)B_N * 4)                  // rsqrt(|m|^2)   256 KiB
#define OFF_LSUM  (OFF_RM  + (size_t)S_N * 4)                  // softmax denom  4 KiB
#define OFF_OPART (OFF_LSUM + (size_t)B_N * 4)                 // PV partials    64 MiB

__device__ __forceinline__ unsigned short f2bf(float f) {
  unsigned u = __builtin_bit_cast(unsigned, f);
  u += 0x7fffu + ((u >> 16) & 1u);          // RNE
  return (unsigned short)(u >> 16);
}

__device__ __forceinline__ void stage16(const unsigned short* g, unsigned short* l) {
  // async global->LDS, 16B/lane; LDS dest is wave-uniform base + lane*16
  __builtin_amdgcn_global_load_lds(
      (const __attribute__((address_space(1))) void*)g,
      (__attribute__((address_space(3))) void*)l, 16, 0, 0);
}

// ---------------- prep X: bf16 convert + rx = 8*log2e*rsqrt(||x||^2) ----------------
__global__ void k_prep_x(const float* __restrict__ X, unsigned short* __restrict__ Xbf,
                         float* __restrict__ rx) {
  const int row = blockIdx.x;
  const int t = threadIdx.x;  // 0..127
  float4 v = ((const float4*)(X + (size_t)row * D_N))[t];
  float ss = v.x*v.x + v.y*v.y + v.z*v.z + v.w*v.w;
  ushort4 o; o.x = f2bf(v.x); o.y = f2bf(v.y); o.z = f2bf(v.z); o.w = f2bf(v.w);
  ((ushort4*)(Xbf + (size_t)row * D_N))[t] = o;
  #pragma unroll
  for (int m = 1; m < 64; m <<= 1) ss += __shfl_xor(ss, m);
  __shared__ float partial[2];
  if ((t & 63) == 0) partial[t >> 6] = ss;
  __syncthreads();
  if (t == 0) rx[row] = 11.541560327111707f * rsqrtf(fmaxf(partial[0] + partial[1], 1e-24f));
}

// ------- prep M: bf16 convert, LDS-transpose to Mt, rm = rsqrt(||m||^2) -------
__global__ void k_prep_m(const float* __restrict__ M, unsigned short* __restrict__ Mbf,
                         unsigned short* __restrict__ Mt, float* __restrict__ rm) {
  __shared__ float ts[64 * 65];             // 64x64 tile, +1 pad -> conflict-free transpose
  const int t = threadIdx.x;                // 256
  const int s0 = blockIdx.x * 64;
  const int r = t >> 2, cq = t & 3;
  const int c = t >> 2, sq = t & 3;
  float ss = 0.f;
  for (int ct = 0; ct < 8; ++ct) {
    float f[16];
    const float4* src = (const float4*)(M + (size_t)(s0 + r) * D_N + ct * 64 + cq * 16);
    #pragma unroll
    for (int k = 0; k < 4; ++k) {
      float4 v = src[k];
      f[4*k+0] = v.x; f[4*k+1] = v.y; f[4*k+2] = v.z; f[4*k+3] = v.w;
    }
    union { unsigned short u[16]; uint4 v4[2]; } pk;
    #pragma unroll
    for (int j = 0; j < 16; ++j) {
      ss += f[j] * f[j];
      pk.u[j] = f2bf(f[j]);
      ts[r * 65 + cq * 16 + j] = f[j];
    }
    uint4* dst = (uint4*)(Mbf + (size_t)(s0 + r) * D_N + ct * 64 + cq * 16);
    dst[0] = pk.v4[0]; dst[1] = pk.v4[1];
    __syncthreads();
    union { unsigned short u[16]; uint4 v4[2]; } pt;
    #pragma unroll
    for (int j = 0; j < 16; ++j) pt.u[j] = f2bf(ts[(sq * 16 + j) * 65 + c]);
    uint4* dt = (uint4*)(Mt + (size_t)(ct * 64 + c) * S_N + s0 + sq * 16);
    dt[0] = pt.v4[0]; dt[1] = pt.v4[1];
    __syncthreads();
  }
  ss += __shfl_xor(ss, 1);
  ss += __shfl_xor(ss, 2);
  if (cq == 0) rm[s0 + r] = rsqrtf(fmaxf(ss, 1e-24f));
}

// ======== fused QK -> exp -> PV, 32x32x16 MFMA, SB=256, R2 pipeline ========
// QK: P^T 256s x 128b, wave grid 4s x 2b, wave tile 64x64 (2x2 of 32x32x16),
//     accP = 64 VGPR. Staged M (pair-interleaved, conflict-free) + X.
// PV: O 128b x 512d, wave grid 2b x 4d, wave tile 64b x 128d (2x4), accO = 128.
//     Staged Mt [512d][32s] slices.
// LDS: 2 x 48 KiB staging dbuf (M 32 + X 16; PV reuses first 32 KiB for Mt)
//      + 64 KiB Ps = 160 KiB exactly. 1 block/CU, 8 waves.
// Pipeline: counted vmcnt, phase p prefetches p+1 into buf p&1^1; QK ph7
// prefetches PV Mt ph0; PV ph7 prefetches next sub's QK ph0. Drain only at end.
__global__ __launch_bounds__(512, 2) void k_fused(
    const unsigned short* __restrict__ Xbf, const unsigned short* __restrict__ Mbf,
    const unsigned short* __restrict__ Mt, const float* __restrict__ rx,
    const float* __restrict__ rminv, float* __restrict__ lsum,
    float* __restrict__ Opart) {
  __shared__ unsigned short Stg[2][24576];  // 48 KiB each: M/Mt [0,16384), X [16384,24576)
  __shared__ unsigned short Ps[32768];      // 64 KiB: P [128b][256s], 3-bit chunk swizzle

  const int t = threadIdx.x;               // 0..511
  const int w = t >> 6, lane = t & 63, l31 = lane & 31, hi = lane >> 5;
  const int qs = w >> 1, qcb = w & 1;      // QK wave grid: 4 s x 2 b
  const int hb = w >> 2, qd = w & 3;       // PV wave grid: 2 b x 4 d
  const int r7 = (l31 >> 1) & 7;           // pair-interleave swizzle key (QK tiles)
  const int p7 = l31 & 7;                  // Ps swizzle key
  const int t3 = l31 & 3;                  // Mt-slice swizzle key
  const int sub8 = (lane & 1) * 8;         // sub-slot within row pair
  const int rp15 = l31 >> 1;               // row-pair within 32-row tile

  // XCD swizzle: 8 batch-blocks sharing an s-chunk land on one XCD
  const int bid = blockIdx.x;
  const int xcd = bid & 7, slot = bid >> 3;
  const int bblk = slot & 7;
  const int chunk = xcd * 4 + (slot >> 3);
  const int b0 = bblk * 128;
  const int s0 = chunk * SC;

  // staging thread roles (dest is linear; inverse permutation on source side)
  const int mrow_t = ((t >> 4) << 1) | (t & 1);                 // QK tiles: row within 64-row issue
  const int mc8    = ((((t >> 1) & 7) ^ ((t >> 4) & 7)) << 3);  // k-offset (shorts)
  const int trow_t = t >> 2;                                    // Mt slice: row within 128-row issue
  const int tc8    = (((t & 3) ^ ((t >> 2) & 3)) << 3);         // s-offset (shorts)

  #define ISS_QK(sS_, k0_, bi_) do {                                           \
    _Pragma("unroll")                                                          \
    for (int is = 0; is < 4; ++is)                                             \
      stage16(Mbf + (size_t)((sS_) + is * 64 + mrow_t) * D_N + (k0_) + mc8,    \
              &Stg[bi_][is * 4096 + w * 512]);                                 \
    _Pragma("unroll")                                                          \
    for (int is = 0; is < 2; ++is)                                             \
      stage16(Xbf + (size_t)(b0 + is * 64 + mrow_t) * D_N + (k0_) + mc8,       \
              &Stg[bi_][16384 + is * 4096 + w * 512]);                         \
  } while (0)
  #define ISS_T(sS_, ph_, bi_) do {                                            \
    _Pragma("unroll")                                                          \
    for (int is = 0; is < 4; ++is)                                             \
      stage16(Mt + (size_t)(is * 128 + trow_t) * S_N + (sS_) + (ph_) * 32 + tc8, \
              &Stg[bi_][is * 4096 + w * 512]);                                 \
  } while (0)

  f32x16 accO[2][4];                       // 128 VGPR: b-tile i, d-tile j
  #pragma unroll
  for (int i = 0; i < 2; ++i)
    #pragma unroll
    for (int j = 0; j < 4; ++j)
      #pragma unroll
      for (int r = 0; r < 16; ++r) accO[i][j][r] = 0.f;

  float ls[2] = {0.f, 0.f};
  float rxj[2];
  #pragma unroll
  for (int j = 0; j < 2; ++j) rxj[j] = rx[b0 + qcb * 64 + j * 32 + l31];

  // prologue: sub 0 QK phase 0 into buffer 0
  ISS_QK(s0, 0, 0);

  for (int sub = 0; sub < NSUB; ++sub) {
    const int sS = s0 + sub * SB;

    // ---------------- QK phases 0..7 (k0 = ph*64) ----------------
    f32x16 accP[2][2];
    #pragma unroll
    for (int i = 0; i < 2; ++i)
      #pragma unroll
      for (int j = 0; j < 2; ++j)
        #pragma unroll
        for (int r = 0; r < 16; ++r) accP[i][j][r] = 0.f;

    #pragma unroll
    for (int ph = 0; ph < 8; ++ph) {
      const int bi = ph & 1;
      if (ph < 7) { ISS_QK(sS, (ph + 1) * 64, bi ^ 1); }
      else        { ISS_T(sS, 0, bi ^ 1); }
      if (ph < 7) asm volatile("s_waitcnt vmcnt(6)" ::: "memory");
      else        asm volatile("s_waitcnt vmcnt(4)" ::: "memory");
      __builtin_amdgcn_s_barrier();
      const unsigned short* Ms = &Stg[bi][0];
      const unsigned short* Xs = &Stg[bi][16384];
      __builtin_amdgcn_s_setprio(1);
      #pragma unroll
      for (int ks = 0; ks < 4; ++ks) {
        const int c = ks * 2 + hi;
        bf16x8 aB[2], xB[2];
        #pragma unroll
        for (int i = 0; i < 2; ++i)
          aB[i] = *(const bf16x8*)&Ms[(qs * 32 + i * 16 + rp15) * 128 + ((c ^ r7) << 4) + sub8];
        #pragma unroll
        for (int j = 0; j < 2; ++j)
          xB[j] = *(const bf16x8*)&Xs[(qcb * 32 + j * 16 + rp15) * 128 + ((c ^ r7) << 4) + sub8];
        #pragma unroll
        for (int i = 0; i < 2; ++i)
          #pragma unroll
          for (int j = 0; j < 2; ++j)
            accP[i][j] = __builtin_amdgcn_mfma_f32_32x32x16_bf16(aB[i], xB[j], accP[i][j], 0, 0, 0);
      }
      __builtin_amdgcn_s_setprio(0);
      __builtin_amdgcn_s_barrier();
    }

    // ------------- epilogue: p = exp2(dot*rx_b*rm_s), rowsum, P -> LDS -------------
    // 32x32 C layout: s = qs*64 + i*32 + (reg&3) + 8*(reg>>2) + 4*hi, b = qcb*64 + j*32 + l31
    #pragma unroll
    for (int i = 0; i < 2; ++i)
      #pragma unroll
      for (int g = 0; g < 4; ++g) {
        const float4 rm = *(const float4*)&rminv[sS + qs * 64 + i * 32 + g * 8 + hi * 4];
        const int c16 = qs * 8 + i * 4 + g;
        #pragma unroll
        for (int j = 0; j < 2; ++j) {
          const float p0 = exp2f(accP[i][j][g * 4 + 0] * rxj[j] * rm.x);
          const float p1 = exp2f(accP[i][j][g * 4 + 1] * rxj[j] * rm.y);
          const float p2 = exp2f(accP[i][j][g * 4 + 2] * rxj[j] * rm.z);
          const float p3 = exp2f(accP[i][j][g * 4 + 3] * rxj[j] * rm.w);
          ls[j] += (p0 + p1) + (p2 + p3);
          const int brow = qcb * 64 + j * 32 + l31;
          uint2 pk;
          pk.x = (unsigned)f2bf(p0) | ((unsigned)f2bf(p1) << 16);
          pk.y = (unsigned)f2bf(p2) | ((unsigned)f2bf(p3) << 16);
          *(uint2*)&Ps[brow * 256 + ((c16 ^ p7) << 3) + hi * 4] = pk;
        }
      }
    asm volatile("s_waitcnt lgkmcnt(0)" ::: "memory");

    // ---------------- PV phases 0..7 (s-window = ph*32) ----------------
    #pragma unroll
    for (int ph = 0; ph < 8; ++ph) {
      const int bi = ph & 1;
      if (ph < 7)                { ISS_T(sS, ph + 1, bi ^ 1); }
      else if (sub < NSUB - 1)   { ISS_QK(sS + SB, 0, bi ^ 1); }
      if (ph < 7)                     asm volatile("s_waitcnt vmcnt(4)" ::: "memory");
      else if (sub < NSUB - 1)        asm volatile("s_waitcnt vmcnt(6)" ::: "memory");
      else                            asm volatile("s_waitcnt vmcnt(0)" ::: "memory");
      __builtin_amdgcn_s_barrier();
      const unsigned short* Ts = &Stg[bi][0];
      __builtin_amdgcn_s_setprio(1);
      #pragma unroll
      for (int ks = 0; ks < 2; ++ks) {
        const int cP = ph * 4 + ks * 2 + hi;
        const int cT = ks * 2 + hi;
        bf16x8 pa[2], mB[4];
        #pragma unroll
        for (int i = 0; i < 2; ++i)
          pa[i] = *(const bf16x8*)&Ps[(hb * 64 + i * 32 + l31) * 256 + ((cP ^ p7) << 3)];
        #pragma unroll
        for (int j = 0; j < 4; ++j)
          mB[j] = *(const bf16x8*)&Ts[(qd * 128 + j * 32 + l31) * 32 + ((cT ^ t3) << 3)];
        #pragma unroll
        for (int i = 0; i < 2; ++i)
          #pragma unroll
          for (int j = 0; j < 4; ++j)
            accO[i][j] = __builtin_amdgcn_mfma_f32_32x32x16_bf16(pa[i], mB[j], accO[i][j], 0, 0, 0);
      }
      __builtin_amdgcn_s_setprio(0);
      __builtin_amdgcn_s_barrier();
    }
  }

  // ---------------- write O partials (coalesced over d via l31) ----------------
  // accO C layout: b = hb*64 + i*32 + (reg&3) + 8*(reg>>2) + 4*hi, d = qd*128 + j*32 + l31
  float* Od = Opart + (size_t)chunk * ((size_t)B_N * D_N);
  #pragma unroll
  for (int i = 0; i < 2; ++i)
    #pragma unroll
    for (int g = 0; g < 4; ++g)
      #pragma unroll
      for (int r = 0; r < 4; ++r) {
        const int bb = b0 + hb * 64 + i * 32 + g * 8 + hi * 4 + r;
        #pragma unroll
        for (int j = 0; j < 4; ++j) {
          const int d = qd * 128 + j * 32 + l31;
          Od[(size_t)bb * D_N + d] = accO[i][j][g * 4 + r];
        }
      }

  // ---------------- lsum: hi-half reduce, cross-wave via LDS, one atomic per b ----------------
  __syncthreads();
  float* red = (float*)&Stg[0][0];           // 8 waves x 64 b-slots
  #pragma unroll
  for (int j = 0; j < 2; ++j) {
    float v = ls[j];
    v += __shfl_xor(v, 32);
    if (lane < 32) red[w * 64 + j * 32 + l31] = v;
  }
  __syncthreads();
  if (t < 128) {
    const int qc2 = t >> 6, idx = t & 63;
    float s = red[(0 + qc2) * 64 + idx] + red[(2 + qc2) * 64 + idx] +
              red[(4 + qc2) * 64 + idx] + red[(6 + qc2) * 64 + idx];
    unsafeAtomicAdd(&lsum[b0 + t], s);
  }
  #undef ISS_QK
  #undef ISS_T
}

// ---------------- combine: out = (sum_ks Opart) / lsum ----------------
__global__ void k_combine(const float* __restrict__ Opart, const float* __restrict__ lsum,
                          float* __restrict__ out) {
  const int idx = blockIdx.x * 256 + threadIdx.x;  // float4 index, 131072 total
  const int b = idx >> 7;
  float4 s = {0.f, 0.f, 0.f, 0.f};
  #pragma unroll
  for (int ks = 0; ks < NS; ++ks) {
    float4 v = ((const float4*)Opart)[(size_t)ks * (B_N * D_N / 4) + idx];
    s.x += v.x; s.y += v.y; s.z += v.z; s.w += v.w;
  }
  const float inv = 1.0f / lsum[b];
  s.x *= inv; s.y *= inv; s.z *= inv; s.w *= inv;
  ((float4*)out)[idx] = s;
}

extern "C" void kernel_launch(void* const* d_in, const int* in_sizes, int n_in,
                              void* d_out, int out_size, void* d_ws, size_t ws_size,
                              hipStream_t stream) {
  const float* X = (const float*)d_in[0];
  const float* M = (const float*)d_in[1];
  char* ws = (char*)d_ws;
  unsigned short* Mbf = (unsigned short*)(ws + OFF_MBF);
  unsigned short* Mt  = (unsigned short*)(ws + OFF_MT);
  unsigned short* Xbf = (unsigned short*)(ws + OFF_XBF);
  float* rxv  = (float*)(ws + OFF_RX);
  float* rmv  = (float*)(ws + OFF_RM);
  float* lsum = (float*)(ws + OFF_LSUM);
  float* Opart = (float*)(ws + OFF_OPART);

  hipMemsetAsync(lsum, 0, B_N * sizeof(float), stream);
  k_prep_x<<<dim3(B_N), 128, 0, stream>>>(X, Xbf, rxv);
  k_prep_m<<<dim3(S_N / 64), 256, 0, stream>>>(M, Mbf, Mt, rmv);
  k_fused<<<dim3(8 * NS), 512, 0, stream>>>(Xbf, Mbf, Mt, rxv, rmv, lsum, Opart);
  k_combine<<<dim3(B_N * D_N / 4 / 256), 256, 0, stream>>>(Opart, lsum, (float*)d_out);
}

// Round 7
// 481.793 us; speedup vs baseline: 1.4530x; 1.0156x over previous
//
#include <hip/hip_runtime.h>
#include <hip/hip_bf16.h>
#include <stdint.h>

// Problem constants
#define B_N 1024
#define S_N 65536
#define D_N 512
#define NS 32                 // s-chunks; grid = 8 batch-blocks x NS = 256 = 1 block/CU
#define SC (S_N / NS)         // 2048 s per block
#define SB 256                // s subtile (P tile = 128 b x 256 s in LDS)
#define NSUB (SC / SB)        // 8

typedef __attribute__((ext_vector_type(8))) short bf16x8;   // 8 bf16 in 4 VGPRs
typedef __attribute__((ext_vector_type(4))) float f32x4;
typedef __attribute__((ext_vector_type(16))) float f32x16;  // 32x32 MFMA accumulator

// ---- workspace layout (bytes) ----
#define OFF_MBF   ((size_t)0)                                  // M bf16 (s,d)   64 MiB
#define OFF_MT    (OFF_MBF + (size_t)S_N * D_N * 2)            // M^T bf16 (d,s) 64 MiB
#define OFF_XBF   (OFF_MT  + (size_t)D_N * S_N * 2)            // X bf16         1 MiB
#define OFF_RX    (OFF_XBF + (size_t)B_N * D_N * 2)            // 8*log2e*rsqrt(|x|^2)  4 KiB
#define OFF_RM    (OFF_RX  + (size_t)B_N * 4)                  // rsqrt(|m|^2)   256 KiB
#define OFF_LSUM  (OFF_RM  + (size_t)S_N * 4)                  // softmax denom  4 KiB
#define OFF_OPART (OFF_LSUM + (size_t)B_N * 4)                 // PV partials    64 MiB

__device__ __forceinline__ unsigned short f2bf(float f) {
  unsigned u = __builtin_bit_cast(unsigned, f);
  u += 0x7fffu + ((u >> 16) & 1u);          // RNE
  return (unsigned short)(u >> 16);
}

__device__ __forceinline__ void stage16(const unsigned short* g, unsigned short* l) {
  // async global->LDS, 16B/lane; LDS dest is wave-uniform base + lane*16
  __builtin_amdgcn_global_load_lds(
      (const __attribute__((address_space(1))) void*)g,
      (__attribute__((address_space(3))) void*)l, 16, 0, 0);
}

// ---------------- prep X: bf16 convert + rx = 8*log2e*rsqrt(||x||^2) ----------------
__global__ void k_prep_x(const float* __restrict__ X, unsigned short* __restrict__ Xbf,
                         float* __restrict__ rx) {
  const int row = blockIdx.x;
  const int t = threadIdx.x;  // 0..127
  float4 v = ((const float4*)(X + (size_t)row * D_N))[t];
  float ss = v.x*v.x + v.y*v.y + v.z*v.z + v.w*v.w;
  ushort4 o; o.x = f2bf(v.x); o.y = f2bf(v.y); o.z = f2bf(v.z); o.w = f2bf(v.w);
  ((ushort4*)(Xbf + (size_t)row * D_N))[t] = o;
  #pragma unroll
  for (int m = 1; m < 64; m <<= 1) ss += __shfl_xor(ss, m);
  __shared__ float partial[2];
  if ((t & 63) == 0) partial[t >> 6] = ss;
  __syncthreads();
  if (t == 0) rx[row] = 11.541560327111707f * rsqrtf(fmaxf(partial[0] + partial[1], 1e-24f));
}

// ------- prep M: bf16 convert, LDS-transpose to Mt, rm = rsqrt(||m||^2) -------
__global__ void k_prep_m(const float* __restrict__ M, unsigned short* __restrict__ Mbf,
                         unsigned short* __restrict__ Mt, float* __restrict__ rm) {
  __shared__ float ts[64 * 65];             // 64x64 tile, +1 pad -> conflict-free transpose
  const int t = threadIdx.x;                // 256
  const int s0 = blockIdx.x * 64;
  const int r = t >> 2, cq = t & 3;
  const int c = t >> 2, sq = t & 3;
  float ss = 0.f;
  for (int ct = 0; ct < 8; ++ct) {
    float f[16];
    const float4* src = (const float4*)(M + (size_t)(s0 + r) * D_N + ct * 64 + cq * 16);
    #pragma unroll
    for (int k = 0; k < 4; ++k) {
      float4 v = src[k];
      f[4*k+0] = v.x; f[4*k+1] = v.y; f[4*k+2] = v.z; f[4*k+3] = v.w;
    }
    union { unsigned short u[16]; uint4 v4[2]; } pk;
    #pragma unroll
    for (int j = 0; j < 16; ++j) {
      ss += f[j] * f[j];
      pk.u[j] = f2bf(f[j]);
      ts[r * 65 + cq * 16 + j] = f[j];
    }
    uint4* dst = (uint4*)(Mbf + (size_t)(s0 + r) * D_N + ct * 64 + cq * 16);
    dst[0] = pk.v4[0]; dst[1] = pk.v4[1];
    __syncthreads();
    union { unsigned short u[16]; uint4 v4[2]; } pt;
    #pragma unroll
    for (int j = 0; j < 16; ++j) pt.u[j] = f2bf(ts[(sq * 16 + j) * 65 + c]);
    uint4* dt = (uint4*)(Mt + (size_t)(ct * 64 + c) * S_N + s0 + sq * 16);
    dt[0] = pt.v4[0]; dt[1] = pt.v4[1];
    __syncthreads();
  }
  ss += __shfl_xor(ss, 1);
  ss += __shfl_xor(ss, 2);
  if (cq == 0) rm[s0 + r] = rsqrtf(fmaxf(ss, 1e-24f));
}

// ======== fused QK -> exp -> PV, 32x32x16 MFMA, SB=256, bank-clean layouts ========
// QK: P^T 256s x 128b, wave grid 4s x 2b, wave tile 64x64 (2x2 of 32x32x16).
//     Staging tiles [row][8x16B], slot = c ^ (row&7)  (128B rows = bank period;
//     reads land at the 8-access b128 minimum -- the verified R2 scheme).
// PV: O 128b x 512d, wave grid 2b x 4d; phase = d-half(2) x s-window(4);
//     Mt phase tile [256 d-rows][64 s] (128B rows, same swizzle; full cache
//     lines consumed per phase -> no L2 partial-line refetch).
//     wave d-map: d = (jj>>1)*256 + qd*64 + (jj&1)*32 + l31 (active every phase).
// LDS: 2 x 48 KiB staging dbuf + 64 KiB Ps = 160 KiB. 1 block/CU, 8 waves.
// Pipeline: counted vmcnt (QK 6 loads/phase, PV 4), drain only at the very end.
__global__ __launch_bounds__(512, 2) void k_fused(
    const unsigned short* __restrict__ Xbf, const unsigned short* __restrict__ Mbf,
    const unsigned short* __restrict__ Mt, const float* __restrict__ rx,
    const float* __restrict__ rminv, float* __restrict__ lsum,
    float* __restrict__ Opart) {
  __shared__ unsigned short Stg[2][24576];  // 48 KiB each: M/Mt [0,16384), X [16384,24576)
  __shared__ unsigned short Ps[32768];      // 64 KiB: P [128b][256s], 3-bit chunk swizzle

  const int t = threadIdx.x;               // 0..511
  const int w = t >> 6, lane = t & 63, l31 = lane & 31, hi = lane >> 5;
  const int qs = w >> 1, qcb = w & 1;      // QK wave grid: 4 s x 2 b
  const int hb = w >> 2, qd = w & 3;       // PV wave grid: 2 b x 4 d
  const int p7 = l31 & 7;                  // swizzle key (all readers: rows = base + l31)

  // XCD swizzle: 8 batch-blocks sharing an s-chunk land on one XCD
  const int bid = blockIdx.x;
  const int xcd = bid & 7, slot = bid >> 3;
  const int bblk = slot & 7;
  const int chunk = xcd * 4 + (slot >> 3);
  const int b0 = bblk * 128;
  const int s0 = chunk * SC;

  // staging thread roles (dest linear = t*16B; inverse permutation on source)
  const int srow = t >> 3;                                // row within 64-row issue
  const int sch8 = ((t & 7) ^ (srow & 7)) * 8;            // source 16B chunk (shorts)

  #define ISS_QK(sS_, k0_, bi_) do {                                           \
    _Pragma("unroll")                                                          \
    for (int is = 0; is < 4; ++is)                                             \
      stage16(Mbf + (size_t)((sS_) + is * 64 + srow) * D_N + (k0_) + sch8,     \
              &Stg[bi_][is * 4096 + w * 512]);                                 \
    _Pragma("unroll")                                                          \
    for (int is = 0; is < 2; ++is)                                             \
      stage16(Xbf + (size_t)(b0 + is * 64 + srow) * D_N + (k0_) + sch8,        \
              &Stg[bi_][16384 + is * 4096 + w * 512]);                         \
  } while (0)
  // PV phase ph: d-half dh = ph>>2 (256 rows), s-window sw = ph&3 (64 s)
  #define ISS_T(sS_, ph_, bi_) do {                                            \
    _Pragma("unroll")                                                          \
    for (int is = 0; is < 4; ++is)                                             \
      stage16(Mt + (size_t)(((ph_) >> 2) * 256 + is * 64 + srow) * S_N         \
                 + (sS_) + (((ph_) & 3) * 64) + sch8,                          \
              &Stg[bi_][is * 4096 + w * 512]);                                 \
  } while (0)

  f32x16 accO[2][4];                       // 128 VGPR: b-tile i, d-tile jj
  #pragma unroll
  for (int i = 0; i < 2; ++i)
    #pragma unroll
    for (int j = 0; j < 4; ++j)
      #pragma unroll
      for (int r = 0; r < 16; ++r) accO[i][j][r] = 0.f;

  float ls[2] = {0.f, 0.f};
  float rxj[2];
  #pragma unroll
  for (int j = 0; j < 2; ++j) rxj[j] = rx[b0 + qcb * 64 + j * 32 + l31];

  // prologue: sub 0 QK phase 0 into buffer 0
  ISS_QK(s0, 0, 0);

  for (int sub = 0; sub < NSUB; ++sub) {
    const int sS = s0 + sub * SB;

    // ---------------- QK phases 0..7 (k0 = ph*64) ----------------
    f32x16 accP[2][2];
    #pragma unroll
    for (int i = 0; i < 2; ++i)
      #pragma unroll
      for (int j = 0; j < 2; ++j)
        #pragma unroll
        for (int r = 0; r < 16; ++r) accP[i][j][r] = 0.f;

    #pragma unroll
    for (int ph = 0; ph < 8; ++ph) {
      const int bi = ph & 1;
      if (ph < 7) { ISS_QK(sS, (ph + 1) * 64, bi ^ 1); }
      else        { ISS_T(sS, 0, bi ^ 1); }
      if (ph < 7) asm volatile("s_waitcnt vmcnt(6)" ::: "memory");
      else        asm volatile("s_waitcnt vmcnt(4)" ::: "memory");
      __builtin_amdgcn_s_barrier();
      const unsigned short* Ms = &Stg[bi][0];
      const unsigned short* Xs = &Stg[bi][16384];
      __builtin_amdgcn_s_setprio(1);
      #pragma unroll
      for (int ks = 0; ks < 4; ++ks) {
        const int c = ks * 2 + hi;
        bf16x8 aB[2], xB[2];
        #pragma unroll
        for (int i = 0; i < 2; ++i)
          aB[i] = *(const bf16x8*)&Ms[(qs * 64 + i * 32 + l31) * 64 + ((c ^ p7) << 3)];
        #pragma unroll
        for (int j = 0; j < 2; ++j)
          xB[j] = *(const bf16x8*)&Xs[(qcb * 64 + j * 32 + l31) * 64 + ((c ^ p7) << 3)];
        #pragma unroll
        for (int i = 0; i < 2; ++i)
          #pragma unroll
          for (int j = 0; j < 2; ++j)
            accP[i][j] = __builtin_amdgcn_mfma_f32_32x32x16_bf16(aB[i], xB[j], accP[i][j], 0, 0, 0);
      }
      __builtin_amdgcn_s_setprio(0);
      __builtin_amdgcn_s_barrier();
    }

    // ------------- epilogue: p = exp2(dot*rx_b*rm_s), rowsum, P -> LDS -------------
    // 32x32 C layout: s = qs*64 + i*32 + g*8 + hi*4 + r, b = qcb*64 + j*32 + l31
    #pragma unroll
    for (int i = 0; i < 2; ++i)
      #pragma unroll
      for (int g = 0; g < 4; ++g) {
        const float4 rm = *(const float4*)&rminv[sS + qs * 64 + i * 32 + g * 8 + hi * 4];
        const int c16 = qs * 8 + i * 4 + g;
        #pragma unroll
        for (int j = 0; j < 2; ++j) {
          const float p0 = exp2f(accP[i][j][g * 4 + 0] * rxj[j] * rm.x);
          const float p1 = exp2f(accP[i][j][g * 4 + 1] * rxj[j] * rm.y);
          const float p2 = exp2f(accP[i][j][g * 4 + 2] * rxj[j] * rm.z);
          const float p3 = exp2f(accP[i][j][g * 4 + 3] * rxj[j] * rm.w);
          ls[j] += (p0 + p1) + (p2 + p3);
          const int brow = qcb * 64 + j * 32 + l31;
          uint2 pk;
          pk.x = (unsigned)f2bf(p0) | ((unsigned)f2bf(p1) << 16);
          pk.y = (unsigned)f2bf(p2) | ((unsigned)f2bf(p3) << 16);
          *(uint2*)&Ps[brow * 256 + ((c16 ^ p7) << 3) + hi * 4] = pk;
        }
      }
    asm volatile("s_waitcnt lgkmcnt(0)" ::: "memory");

    // ---------------- PV phases 0..7 (dh = ph>>2, sw = ph&3) ----------------
    #pragma unroll
    for (int ph = 0; ph < 8; ++ph) {
      const int bi = ph & 1;
      if (ph < 7)                { ISS_T(sS, ph + 1, bi ^ 1); }
      else if (sub < NSUB - 1)   { ISS_QK(sS + SB, 0, bi ^ 1); }
      if (ph < 7)                     asm volatile("s_waitcnt vmcnt(4)" ::: "memory");
      else if (sub < NSUB - 1)        asm volatile("s_waitcnt vmcnt(6)" ::: "memory");
      else                            asm volatile("s_waitcnt vmcnt(0)" ::: "memory");
      __builtin_amdgcn_s_barrier();
      const unsigned short* Ts = &Stg[bi][0];
      const int dh = ph >> 2, sw = ph & 3;
      __builtin_amdgcn_s_setprio(1);
      #pragma unroll
      for (int ks = 0; ks < 4; ++ks) {
        const int cP = sw * 8 + ks * 2 + hi;
        const int cT = ks * 2 + hi;
        bf16x8 pa[2], mB[2];
        #pragma unroll
        for (int i = 0; i < 2; ++i)
          pa[i] = *(const bf16x8*)&Ps[(hb * 64 + i * 32 + l31) * 256 + ((cP ^ p7) << 3)];
        #pragma unroll
        for (int jl = 0; jl < 2; ++jl)
          mB[jl] = *(const bf16x8*)&Ts[(qd * 64 + jl * 32 + l31) * 64 + ((cT ^ p7) << 3)];
        #pragma unroll
        for (int i = 0; i < 2; ++i)
          #pragma unroll
          for (int jl = 0; jl < 2; ++jl)
            accO[i][dh * 2 + jl] = __builtin_amdgcn_mfma_f32_32x32x16_bf16(pa[i], mB[jl], accO[i][dh * 2 + jl], 0, 0, 0);
      }
      __builtin_amdgcn_s_setprio(0);
      __builtin_amdgcn_s_barrier();
    }
  }

  // ---------------- write O partials (coalesced over d via l31) ----------------
  // accO C layout: b = hb*64 + i*32 + g*8 + hi*4 + r, d = (jj>>1)*256 + qd*64 + (jj&1)*32 + l31
  float* Od = Opart + (size_t)chunk * ((size_t)B_N * D_N);
  #pragma unroll
  for (int i = 0; i < 2; ++i)
    #pragma unroll
    for (int g = 0; g < 4; ++g)
      #pragma unroll
      for (int r = 0; r < 4; ++r) {
        const int bb = b0 + hb * 64 + i * 32 + g * 8 + hi * 4 + r;
        #pragma unroll
        for (int jj = 0; jj < 4; ++jj) {
          const int d = (jj >> 1) * 256 + qd * 64 + (jj & 1) * 32 + l31;
          Od[(size_t)bb * D_N + d] = accO[i][jj][g * 4 + r];
        }
      }

  // ---------------- lsum: hi-half reduce, cross-wave via LDS, one atomic per b ----------------
  __syncthreads();
  float* red = (float*)&Stg[0][0];           // 8 waves x 64 b-slots
  #pragma unroll
  for (int j = 0; j < 2; ++j) {
    float v = ls[j];
    v += __shfl_xor(v, 32);
    if (lane < 32) red[w * 64 + j * 32 + l31] = v;
  }
  __syncthreads();
  if (t < 128) {
    const int qc2 = t >> 6, idx = t & 63;
    float s = red[(0 + qc2) * 64 + idx] + red[(2 + qc2) * 64 + idx] +
              red[(4 + qc2) * 64 + idx] + red[(6 + qc2) * 64 + idx];
    unsafeAtomicAdd(&lsum[b0 + t], s);
  }
  #undef ISS_QK
  #undef ISS_T
}

// ---------------- combine: out = (sum_ks Opart) / lsum ----------------
__global__ void k_combine(const float* __restrict__ Opart, const float* __restrict__ lsum,
                          float* __restrict__ out) {
  const int idx = blockIdx.x * 256 + threadIdx.x;  // float4 index, 131072 total
  const int b = idx >> 7;
  float4 s = {0.f, 0.f, 0.f, 0.f};
  #pragma unroll
  for (int ks = 0; ks < NS; ++ks) {
    float4 v = ((const float4*)Opart)[(size_t)ks * (B_N * D_N / 4) + idx];
    s.x += v.x; s.y += v.y; s.z += v.z; s.w += v.w;
  }
  const float inv = 1.0f / lsum[b];
  s.x *= inv; s.y *= inv; s.z *= inv; s.w *= inv;
  ((float4*)out)[idx] = s;
}

extern "C" void kernel_launch(void* const* d_in, const int* in_sizes, int n_in,
                              void* d_out, int out_size, void* d_ws, size_t ws_size,
                              hipStream_t stream) {
  const float* X = (const float*)d_in[0];
  const float* M = (const float*)d_in[1];
  char* ws = (char*)d_ws;
  unsigned short* Mbf = (unsigned short*)(ws + OFF_MBF);
  unsigned short* Mt  = (unsigned short*)(ws + OFF_MT);
  unsigned short* Xbf = (unsigned short*)(ws + OFF_XBF);
  float* rxv  = (float*)(ws + OFF_RX);
  float* rmv  = (float*)(ws + OFF_RM);
  float* lsum = (float*)(ws + OFF_LSUM);
  float* Opart = (float*)(ws + OFF_OPART);

  hipMemsetAsync(lsum, 0, B_N * sizeof(float), stream);
  k_prep_x<<<dim3(B_N), 128, 0, stream>>>(X, Xbf, rxv);
  k_prep_m<<<dim3(S_N / 64), 256, 0, stream>>>(M, Mbf, Mt, rmv);
  k_fused<<<dim3(8 * NS), 512, 0, stream>>>(Xbf, Mbf, Mt, rxv, rmv, lsum, Opart);
  k_combine<<<dim3(B_N * D_N / 4 / 256), 256, 0, stream>>>(Opart, lsum, (float*)d_out);
}

// Round 8
// 433.171 us; speedup vs baseline: 1.6160x; 1.1122x over previous
//
#include <hip/hip_runtime.h>
#include <hip/hip_bf16.h>
#include <stdint.h>

// Problem constants
#define B_N 1024
#define S_N 65536
#define D_N 512
#define NS 32                 // s-chunks; grid = 8 batch-blocks x NS = 256 = 1 block/CU
#define SC (S_N / NS)         // 2048 s per block
#define SB 128                // s subtile (P tile = 128 b x 128 s in LDS)
#define NSUB (SC / SB)        // 16
#define PSTRIDE 136           // Ps row stride in shorts (128 + 8 pad = 272B rows)

typedef __attribute__((ext_vector_type(8))) short bf16x8;   // 8 bf16 in 4 VGPRs
typedef __attribute__((ext_vector_type(4))) float f32x4;

// ---- workspace layout (bytes) ----
#define OFF_MBF   ((size_t)0)                                  // M bf16 (s,d)   64 MiB
#define OFF_MT    (OFF_MBF + (size_t)S_N * D_N * 2)            // M^T bf16 (d,s) 64 MiB
#define OFF_XBF   (OFF_MT  + (size_t)D_N * S_N * 2)            // X bf16         1 MiB
#define OFF_RX    (OFF_XBF + (size_t)B_N * D_N * 2)            // 8*log2e*rsqrt(|x|^2)  4 KiB
#define OFF_RM    (OFF_RX  + (size_t)B_N * 4)                  // rsqrt(|m|^2)   256 KiB
#define OFF_LSUM  (OFF_RM  + (size_t)S_N * 4)                  // softmax denom  4 KiB
#define OFF_OPART (OFF_LSUM + (size_t)B_N * 4)                 // PV partials    64 MiB

__device__ __forceinline__ unsigned short f2bf(float f) {
  unsigned u = __builtin_bit_cast(unsigned, f);
  u += 0x7fffu + ((u >> 16) & 1u);          // RNE
  return (unsigned short)(u >> 16);
}

__device__ __forceinline__ void stage16(const unsigned short* g, unsigned short* l) {
  // async global->LDS, 16B/lane; LDS dest is wave-uniform base + lane*16
  __builtin_amdgcn_global_load_lds(
      (const __attribute__((address_space(1))) void*)g,
      (__attribute__((address_space(3))) void*)l, 16, 0, 0);
}

// ---------------- prep X: bf16 convert + rx = 8*log2e*rsqrt(||x||^2) ----------------
__global__ void k_prep_x(const float* __restrict__ X, unsigned short* __restrict__ Xbf,
                         float* __restrict__ rx) {
  const int row = blockIdx.x;
  const int t = threadIdx.x;  // 0..127
  float4 v = ((const float4*)(X + (size_t)row * D_N))[t];
  float ss = v.x*v.x + v.y*v.y + v.z*v.z + v.w*v.w;
  ushort4 o; o.x = f2bf(v.x); o.y = f2bf(v.y); o.z = f2bf(v.z); o.w = f2bf(v.w);
  ((ushort4*)(Xbf + (size_t)row * D_N))[t] = o;
  #pragma unroll
  for (int m = 1; m < 64; m <<= 1) ss += __shfl_xor(ss, m);
  __shared__ float partial[2];
  if ((t & 63) == 0) partial[t >> 6] = ss;
  __syncthreads();
  if (t == 0) rx[row] = 11.541560327111707f * rsqrtf(fmaxf(partial[0] + partial[1], 1e-24f));
}

// ------- prep M: bf16 convert, LDS-transpose to Mt, rm = rsqrt(||m||^2) -------
__global__ void k_prep_m(const float* __restrict__ M, unsigned short* __restrict__ Mbf,
                         unsigned short* __restrict__ Mt, float* __restrict__ rm) {
  __shared__ float ts[64 * 65];             // 64x64 tile, +1 pad -> conflict-free transpose
  const int t = threadIdx.x;                // 256
  const int s0 = blockIdx.x * 64;
  const int r = t >> 2, cq = t & 3;
  const int c = t >> 2, sq = t & 3;
  float ss = 0.f;
  for (int ct = 0; ct < 8; ++ct) {
    float f[16];
    const float4* src = (const float4*)(M + (size_t)(s0 + r) * D_N + ct * 64 + cq * 16);
    #pragma unroll
    for (int k = 0; k < 4; ++k) {
      float4 v = src[k];
      f[4*k+0] = v.x; f[4*k+1] = v.y; f[4*k+2] = v.z; f[4*k+3] = v.w;
    }
    union { unsigned short u[16]; uint4 v4[2]; } pk;
    #pragma unroll
    for (int j = 0; j < 16; ++j) {
      ss += f[j] * f[j];
      pk.u[j] = f2bf(f[j]);
      ts[r * 65 + cq * 16 + j] = f[j];
    }
    uint4* dst = (uint4*)(Mbf + (size_t)(s0 + r) * D_N + ct * 64 + cq * 16);
    dst[0] = pk.v4[0]; dst[1] = pk.v4[1];
    __syncthreads();
    union { unsigned short u[16]; uint4 v4[2]; } pt;
    #pragma unroll
    for (int j = 0; j < 16; ++j) pt.u[j] = f2bf(ts[(sq * 16 + j) * 65 + c]);
    uint4* dt = (uint4*)(Mt + (size_t)(ct * 64 + c) * S_N + s0 + sq * 16);
    dt[0] = pt.v4[0]; dt[1] = pt.v4[1];
    __syncthreads();
  }
  ss += __shfl_xor(ss, 1);
  ss += __shfl_xor(ss, 2);
  if (cq == 0) rm[s0 + r] = rsqrtf(fmaxf(ss, 1e-24f));
}

// ======== fused QK -> exp -> PV: R2 structure + 3-ring single-barrier pipeline ========
// 12 phases per sub (8 QK + 4 PV), one barrier each. Phase p: vmcnt(4) ->
// s_barrier -> issue loads for phase p+2 into ring slot (p+2)%3 -> compute slot
// p%3. Buffer overwritten at phase p was last read at p-1; every wave passed
// that compute before p's barrier -> safe with a single barrier. 12%3==0 so
// slot assignments are identical every sub (all compile-time). All phases
// issue exactly 4 loads -> uniform vmcnt(4); vmcnt(0) only at the final phase.
// Ps rows padded to 136 shorts (272B): natural 16B/row bank rotation, no XOR.
// LDS: 3 x 32 KiB ring + 34 KiB Ps = 130 KiB, 1 block/CU, 8 waves.
__global__ __launch_bounds__(512, 2) void k_fused(
    const unsigned short* __restrict__ Xbf, const unsigned short* __restrict__ Mbf,
    const unsigned short* __restrict__ Mt, const float* __restrict__ rx,
    const float* __restrict__ rminv, float* __restrict__ lsum,
    float* __restrict__ Opart) {
  __shared__ unsigned short sbuf[3][16384]; // 3 x 32 KiB ring (QK: A|B, PV: Mt chunk)
  __shared__ unsigned short Ps[128 * PSTRIDE]; // 34 KiB P tile, padded rows

  const int t = threadIdx.x;               // 0..511
  const int w = t >> 6, lane = t & 63, quad = lane >> 4, l15 = lane & 15;
  const int qr = w >> 1, qc = w & 1;       // wave grid 4x2 (s x b for QK; b x d for PV)
  const int x7 = l15 & 7;

  // XCD swizzle: 8 batch-blocks sharing an s-chunk land on one XCD
  const int bid = blockIdx.x;
  const int xcd = bid & 7, slot = bid >> 3;
  const int bblk = slot & 7;
  const int chunk = xcd * 4 + (slot >> 3);
  const int b0 = bblk * 128;
  const int s0 = chunk * SC;

  f32x4 accO[4][2][4];                     // O accumulator (d-chunk, i, j)
  #pragma unroll
  for (int dc = 0; dc < 4; ++dc)
    #pragma unroll
    for (int i = 0; i < 2; ++i)
      #pragma unroll
      for (int j = 0; j < 4; ++j) accO[dc][i][j] = (f32x4){0.f, 0.f, 0.f, 0.f};

  float ls[4] = {0.f, 0.f, 0.f, 0.f};
  float rxj[4];
  #pragma unroll
  for (int j = 0; j < 4; ++j) rxj[j] = rx[b0 + qc * 64 + j * 16 + l15];

  // stager roles (identical to R2)
  const int srow8 = t >> 3;                                 // QK: 64 rows/issue, 8x16B chunks
  const int sch8  = ((t & 7) ^ (srow8 & 7)) * 8;            // source-side inverse swizzle
  const unsigned short* gX0 = Xbf + (size_t)(b0 + srow8) * D_N + sch8;   // + k0
  const unsigned short* gM0 = Mbf + (size_t)srow8 * D_N + sch8;          // + sS*D_N + k0
  const int mrow = t >> 4;                                  // PV: 32 rows/issue, 16x16B chunks
  const int mch  = ((t & 15) ^ (mrow & 7)) * 8;
  const unsigned short* gT0 = Mt + (size_t)mrow * S_N + mch;             // + dc*128*S_N + sS

  #define ISSUE_QK(sS_, k0_, sl_) do {                                       \
    unsigned short* bA_ = &sbuf[(sl_)][0];                                   \
    unsigned short* bB_ = &sbuf[(sl_)][8192];                                \
    const unsigned short* gM_ = gM0 + (size_t)(sS_) * D_N + (k0_);           \
    stage16(gM_,                   bA_ + w * 512);                           \
    stage16(gM_ + (size_t)64*D_N,  bA_ + 4096 + w * 512);                    \
    const unsigned short* gX_ = gX0 + (k0_);                                 \
    stage16(gX_,                   bB_ + w * 512);                           \
    stage16(gX_ + (size_t)64*D_N,  bB_ + 4096 + w * 512);                    \
  } while (0)

  #define ISSUE_PV(sS_, dc_, sl_) do {                                       \
    unsigned short* bT_ = &sbuf[(sl_)][0];                                   \
    const unsigned short* gT_ = gT0 + (size_t)((dc_) * 128) * S_N + (sS_);   \
    stage16(gT_,                   bT_ + w * 512);                           \
    stage16(gT_ + (size_t)32*S_N,  bT_ + 4096 + w * 512);                    \
    stage16(gT_ + (size_t)64*S_N,  bT_ + 8192 + w * 512);                    \
    stage16(gT_ + (size_t)96*S_N,  bT_ + 12288 + w * 512);                   \
  } while (0)

  // prologue: phases 0 and 1 of sub 0 into slots 0, 1
  ISSUE_QK(s0, 0, 0);
  ISSUE_QK(s0, 64, 1);

  for (int sub = 0; sub < NSUB; ++sub) {
    const int sS = s0 + sub * SB;

    // ---------------- QK phases 0..7 (k0 = ph*64, slot ph%3) ----------------
    f32x4 accP[2][4];
    #pragma unroll
    for (int i = 0; i < 2; ++i)
      #pragma unroll
      for (int j = 0; j < 4; ++j) accP[i][j] = (f32x4){0.f, 0.f, 0.f, 0.f};

    #pragma unroll
    for (int ph = 0; ph < 8; ++ph) {
      asm volatile("s_waitcnt vmcnt(4)" ::: "memory");
      __builtin_amdgcn_s_barrier();
      if (ph < 6) { ISSUE_QK(sS, (ph + 2) * 64, (ph + 2) % 3); }
      else        { ISSUE_PV(sS, ph - 6, (ph + 2) % 3); }
      const unsigned short* As = &sbuf[ph % 3][0];
      const unsigned short* Bs = &sbuf[ph % 3][8192];
      __builtin_amdgcn_s_setprio(1);
      #pragma unroll
      for (int kk = 0; kk < 64; kk += 32) {
        const int cq = (kk >> 3) + quad;
        bf16x8 a[2], b[4];
        #pragma unroll
        for (int i = 0; i < 2; ++i)
          a[i] = *(const bf16x8*)&As[(qr * 32 + i * 16 + l15) * 64 + ((cq ^ x7) << 3)];
        #pragma unroll
        for (int j = 0; j < 4; ++j)
          b[j] = *(const bf16x8*)&Bs[(qc * 64 + j * 16 + l15) * 64 + ((cq ^ x7) << 3)];
        #pragma unroll
        for (int i = 0; i < 2; ++i)
          #pragma unroll
          for (int j = 0; j < 4; ++j)
            accP[i][j] = __builtin_amdgcn_mfma_f32_16x16x32_bf16(a[i], b[j], accP[i][j], 0, 0, 0);
      }
      __builtin_amdgcn_s_setprio(0);
    }

    // ------------- epilogue: p = exp2(dot * rx_b * rm_s), rowsum, P -> LDS -------------
    // C layout: s = qr*32 + i*16 + quad*4 + r (4 consecutive), b = qc*64 + j*16 + l15
    {
      const float4 rm0 = *(const float4*)&rminv[sS + qr * 32 + quad * 4];
      const float4 rm1 = *(const float4*)&rminv[sS + qr * 32 + 16 + quad * 4];
      #pragma unroll
      for (int i = 0; i < 2; ++i) {
        const float4 rm = i ? rm1 : rm0;
        const int sl = qr * 32 + i * 16 + quad * 4;   // local s base (mult of 4)
        #pragma unroll
        for (int j = 0; j < 4; ++j) {
          const float p0 = exp2f(accP[i][j][0] * rxj[j] * rm.x);
          const float p1 = exp2f(accP[i][j][1] * rxj[j] * rm.y);
          const float p2 = exp2f(accP[i][j][2] * rxj[j] * rm.z);
          const float p3 = exp2f(accP[i][j][3] * rxj[j] * rm.w);
          ls[j] += (p0 + p1) + (p2 + p3);
          const int brow = qc * 64 + j * 16 + l15;
          uint2 pk;
          pk.x = (unsigned)f2bf(p0) | ((unsigned)f2bf(p1) << 16);
          pk.y = (unsigned)f2bf(p2) | ((unsigned)f2bf(p3) << 16);
          *(uint2*)&Ps[brow * PSTRIDE + sl] = pk;       // padded row, no swizzle needed
        }
      }
      asm volatile("s_waitcnt lgkmcnt(0)" ::: "memory");  // Ps writes done before next barrier
    }

    // ---------------- PV phases 8..11 (dc = 0..3, slot (8+dc)%3) ----------------
    #pragma unroll
    for (int dc = 0; dc < 4; ++dc) {
      if (dc == 3 && sub == NSUB - 1) asm volatile("s_waitcnt vmcnt(0)" ::: "memory");
      else                            asm volatile("s_waitcnt vmcnt(4)" ::: "memory");
      __builtin_amdgcn_s_barrier();
      if (dc < 2)                { ISSUE_PV(sS, dc + 2, (10 + dc) % 3); }
      else if (sub < NSUB - 1)   { ISSUE_QK(sS + SB, (dc - 2) * 64, (10 + dc) % 3); }
      const unsigned short* Tsb = &sbuf[(8 + dc) % 3][0];
      __builtin_amdgcn_s_setprio(1);
      #pragma unroll
      for (int kk = 0; kk < 128; kk += 32) {
        const int cq = (kk >> 3) + quad;
        bf16x8 pa[2], mb[4];
        #pragma unroll
        for (int i = 0; i < 2; ++i)
          pa[i] = *(const bf16x8*)&Ps[(qr * 32 + i * 16 + l15) * PSTRIDE + (cq << 3)];
        #pragma unroll
        for (int j = 0; j < 4; ++j)
          mb[j] = *(const bf16x8*)&Tsb[(qc * 64 + j * 16 + l15) * 128 + ((cq ^ x7) << 3)];
        #pragma unroll
        for (int i = 0; i < 2; ++i)
          #pragma unroll
          for (int j = 0; j < 4; ++j)
            accO[dc][i][j] = __builtin_amdgcn_mfma_f32_16x16x32_bf16(pa[i], mb[j], accO[dc][i][j], 0, 0, 0);
      }
      __builtin_amdgcn_s_setprio(0);
    }
  }

  // ---------------- write O partials (coalesced over d via l15) ----------------
  float* Od = Opart + (size_t)chunk * ((size_t)B_N * D_N);
  #pragma unroll
  for (int dc = 0; dc < 4; ++dc)
    #pragma unroll
    for (int i = 0; i < 2; ++i)
      #pragma unroll
      for (int r = 0; r < 4; ++r) {
        const int bb = b0 + qr * 32 + i * 16 + quad * 4 + r;
        #pragma unroll
        for (int j = 0; j < 4; ++j) {
          const int d = dc * 128 + qc * 64 + j * 16 + l15;
          Od[(size_t)bb * D_N + d] = accO[dc][i][j][r];
        }
      }

  // ---------------- lsum: quad-reduce, cross-wave via LDS, one atomic per b ----------------
  __syncthreads();
  float* red = (float*)&sbuf[0][0];          // 8 waves x 64 b-slots
  #pragma unroll
  for (int j = 0; j < 4; ++j) {
    float v = ls[j];
    v += __shfl_xor(v, 16);
    v += __shfl_xor(v, 32);
    if (lane < 16) red[w * 64 + j * 16 + lane] = v;
  }
  __syncthreads();
  if (t < 128) {
    const int qc2 = t >> 6, idx = t & 63;
    float s = red[(0 + qc2) * 64 + idx] + red[(2 + qc2) * 64 + idx] +
              red[(4 + qc2) * 64 + idx] + red[(6 + qc2) * 64 + idx];
    unsafeAtomicAdd(&lsum[b0 + t], s);
  }
  #undef ISSUE_QK
  #undef ISSUE_PV
}

// ---------------- combine: out = (sum_ks Opart) / lsum ----------------
__global__ void k_combine(const float* __restrict__ Opart, const float* __restrict__ lsum,
                          float* __restrict__ out) {
  const int idx = blockIdx.x * 256 + threadIdx.x;  // float4 index, 131072 total
  const int b = idx >> 7;
  float4 s = {0.f, 0.f, 0.f, 0.f};
  #pragma unroll
  for (int ks = 0; ks < NS; ++ks) {
    float4 v = ((const float4*)Opart)[(size_t)ks * (B_N * D_N / 4) + idx];
    s.x += v.x; s.y += v.y; s.z += v.z; s.w += v.w;
  }
  const float inv = 1.0f / lsum[b];
  s.x *= inv; s.y *= inv; s.z *= inv; s.w *= inv;
  ((float4*)out)[idx] = s;
}

extern "C" void kernel_launch(void* const* d_in, const int* in_sizes, int n_in,
                              void* d_out, int out_size, void* d_ws, size_t ws_size,
                              hipStream_t stream) {
  const float* X = (const float*)d_in[0];
  const float* M = (const float*)d_in[1];
  char* ws = (char*)d_ws;
  unsigned short* Mbf = (unsigned short*)(ws + OFF_MBF);
  unsigned short* Mt  = (unsigned short*)(ws + OFF_MT);
  unsigned short* Xbf = (unsigned short*)(ws + OFF_XBF);
  float* rxv  = (float*)(ws + OFF_RX);
  float* rmv  = (float*)(ws + OFF_RM);
  float* lsum = (float*)(ws + OFF_LSUM);
  float* Opart = (float*)(ws + OFF_OPART);

  hipMemsetAsync(lsum, 0, B_N * sizeof(float), stream);
  k_prep_x<<<dim3(B_N), 128, 0, stream>>>(X, Xbf, rxv);
  k_prep_m<<<dim3(S_N / 64), 256, 0, stream>>>(M, Mbf, Mt, rmv);
  k_fused<<<dim3(8 * NS), 512, 0, stream>>>(Xbf, Mbf, Mt, rxv, rmv, lsum, Opart);
  k_combine<<<dim3(B_N * D_N / 4 / 256), 256, 0, stream>>>(Opart, lsum, (float*)d_out);
}